// Round 12
// baseline (734.658 us; speedup 1.0000x reference)
//
#include <hip/hip_runtime.h>
#include <hip/hip_bf16.h>

#define T_   32
#define B_   32
#define NIN_ 512
#define H_   1024
#define NOUT_ 256
#define NBLK 64          // 64 blocks x 16 cols (verified best: r5, 585us)
#define NTHR 1024
#define NCOL 16
#define NSLOT 80
#define PACKB 128        // prep_all: blocks 0..PACKB-1 pack x
#define GBM 64           // gemmT tile (r9-verified) + reg-prefetch dbuf
#define GBN 64
#define GBK 128

typedef short bf16x8 __attribute__((ext_vector_type(8)));
typedef float f32x4  __attribute__((ext_vector_type(4)));
typedef unsigned int u32x4 __attribute__((ext_vector_type(4)));

__device__ __forceinline__ float bf2f(unsigned short u) {
  union { unsigned int i; float f; } x; x.i = ((unsigned int)u) << 16; return x.f;
}
__device__ __forceinline__ unsigned short f2bf(float f) {
  __hip_bfloat16 h = __float2bfloat16(f);
  return *reinterpret_cast<unsigned short*>(&h);
}
__device__ __forceinline__ unsigned int packf(float v) {
  unsigned short h = f2bf(v);
  unsigned short l = f2bf(v - bf2f(h));
  return ((unsigned int)h << 16) | l;
}
__device__ __forceinline__ void unpack8v(u32x4 a, u32x4 b, bf16x8& hi, bf16x8& lo) {
  unsigned int t[8] = {a[0], a[1], a[2], a[3], b[0], b[1], b[2], b[3]};
  union { bf16x8 v; unsigned int u[4]; } H, L;
#pragma unroll
  for (int j = 0; j < 4; j++) {
    unsigned int e = t[2 * j], o = t[2 * j + 1];
    H.u[j] = (o & 0xFFFF0000u) | (e >> 16);
    L.u[j] = (o << 16) | (e & 0xFFFFu);
  }
  hi = H.v; lo = L.v;
}

// ---- publish primitives: relaxed agent-scope atomics ----
__device__ __forceinline__ void astu(unsigned int* p, unsigned int v) {
  __hip_atomic_store(p, v, __ATOMIC_RELAXED, __HIP_MEMORY_SCOPE_AGENT);
}
__device__ __forceinline__ void astf(float* p, float v) {
  __hip_atomic_store(p, v, __ATOMIC_RELAXED, __HIP_MEMORY_SCOPE_AGENT);
}
__device__ __forceinline__ void aaddf(float* p, float v) {
  __hip_atomic_fetch_add(p, v, __ATOMIC_RELAXED, __HIP_MEMORY_SCOPE_AGENT);
}

// ---- rendezvous: fresh slot; relaxed arrival + relaxed spin (r0/r5 verified) ----
__device__ __forceinline__ void rendezvous(int* cnt, int slot) {
  __syncthreads();
  if (threadIdx.x == 0) {
    __hip_atomic_fetch_add(&cnt[slot], 1, __ATOMIC_RELAXED, __HIP_MEMORY_SCOPE_AGENT);
    while (__hip_atomic_load(&cnt[slot], __ATOMIC_RELAXED, __HIP_MEMORY_SCOPE_AGENT) < NBLK)
      __builtin_amdgcn_s_sleep(1);
    __atomic_signal_fence(__ATOMIC_ACQUIRE);
  }
  __syncthreads();
}

// ---------- dtype detect + counter init ----------
__global__ void init_detect(const unsigned short* __restrict__ x_raw,
                            int* __restrict__ flag, int* __restrict__ cnt) {
  __shared__ int bad;
  if (threadIdx.x == 0) bad = 0;
  __syncthreads();
  int c = 0;
  for (int i = threadIdx.x; i < 2048; i += 256) {
    float v = bf2f(x_raw[i]);
    if (!(fabsf(v) < 1e9f)) c++;
  }
  if (c) atomicAdd(&bad, 1);
  __syncthreads();
  if (threadIdx.x == 0) flag[0] = bad ? 1 : 0;  // 1 = inputs are f32
  for (int i = threadIdx.x; i < NSLOT; i += 256)
    __hip_atomic_store(&cnt[i], 0, __ATOMIC_RELAXED, __HIP_MEMORY_SCOPE_AGENT);
}

// ---------- fused prep: pack x | params | 6x transpose+split (one launch) ----------
__global__ void prep_all(
    const void* __restrict__ x_in, unsigned int* __restrict__ X_pk,
    const void* lam, const void* eta, const void* g, const void* b,
    float* __restrict__ par,
    const void* __restrict__ W_i,  unsigned short* __restrict__ WiT_hi,  unsigned short* __restrict__ WiT_lo,
    const void* __restrict__ W_z,  unsigned short* __restrict__ WzT_hi,  unsigned short* __restrict__ WzT_lo,
    const void* __restrict__ W_c,  unsigned short* __restrict__ WcT_hi,  unsigned short* __restrict__ WcT_lo,
    const void* __restrict__ W_h,  unsigned short* __restrict__ WhT_hi,  unsigned short* __restrict__ WhT_lo,
    const void* __restrict__ W_ho, unsigned short* __restrict__ WhoT_hi, unsigned short* __restrict__ WhoT_lo,
    const void* __restrict__ W_o,  unsigned short* __restrict__ WoT_hi,  unsigned short* __restrict__ WoT_lo,
    const int* __restrict__ flag)
{
  const bool isf32 = flag[0] != 0;
  int blk = blockIdx.x;
  if (blk < PACKB) {                      // ---- x -> relu+pack ----
    const int n = T_ * B_ * NIN_;
    for (int i = blk * 256 + threadIdx.x; i < n; i += PACKB * 256) {
      float v = isf32 ? ((const float*)x_in)[i] : bf2f(((const unsigned short*)x_in)[i]);
      X_pk[i] = packf(fmaxf(v, 0.f));
    }
    return;
  }
  blk -= PACKB;
  if (blk < 4) {                          // ---- params ----
    int t = blk * 256 + threadIdx.x;
    if (t == 0) {
      par[0] = isf32 ? ((const float*)lam)[0] : bf2f(((const unsigned short*)lam)[0]);
      par[1] = isf32 ? ((const float*)eta)[0] : bf2f(((const unsigned short*)eta)[0]);
    }
    if (t < H_) {
      par[2 + t]      = isf32 ? ((const float*)g)[t] : bf2f(((const unsigned short*)g)[t]);
      par[2 + H_ + t] = isf32 ? ((const float*)b)[t] : bf2f(((const unsigned short*)b)[t]);
    }
    return;
  }
  blk -= 4;                               // ---- transpose + hi/lo split ----
  const void* src; unsigned short *dhi, *dlo; int R, C;
  int tb = blk;
  if (tb < 512)       { src = W_i;  dhi = WiT_hi;  dlo = WiT_lo;  R = NIN_; C = H_; }
  else if (tb < 1536) { tb -= 512;  src = W_z;  dhi = WzT_hi;  dlo = WzT_lo;  R = H_; C = H_; }
  else if (tb < 2560) { tb -= 1536; src = W_c;  dhi = WcT_hi;  dlo = WcT_lo;  R = H_; C = H_; }
  else if (tb < 3584) { tb -= 2560; src = W_h;  dhi = WhT_hi;  dlo = WhT_lo;  R = H_; C = H_; }
  else if (tb < 4608) { tb -= 3584; src = W_ho; dhi = WhoT_hi; dlo = WhoT_lo; R = H_; C = H_; }
  else                { tb -= 4608; src = W_o;  dhi = WoT_hi;  dlo = WoT_lo;  R = H_; C = NOUT_; }
  __shared__ unsigned short thi[32][33], tlo[32][33];
  int ncx = C >> 5;
  int c0 = (tb % ncx) * 32, r0 = (tb / ncx) * 32;
  int tx = threadIdx.x & 31, ty = threadIdx.x >> 5;
  for (int i = ty; i < 32; i += 8) {
    size_t idx = (size_t)(r0 + i) * C + c0 + tx;
    float v = isf32 ? ((const float*)src)[idx] : bf2f(((const unsigned short*)src)[idx]);
    unsigned short h = f2bf(v);
    thi[i][tx] = h;
    tlo[i][tx] = f2bf(v - bf2f(h));
  }
  __syncthreads();
  for (int i = ty; i < 32; i += 8) {
    dhi[(size_t)(c0 + i) * R + r0 + tx] = thi[tx][i];
    dlo[(size_t)(c0 + i) * R + r0 + tx] = tlo[tx][i];
  }
}

// ---------- phase-A GEMM, LDS-tiled 64x64 (r9-verified) + reg-prefetch dbuf ----------
template<int K, int OUTMODE>
__global__ void __launch_bounds__(1024) gemmT(
    const unsigned int* __restrict__ A,
    const unsigned short* __restrict__ BT_hi,
    const unsigned short* __restrict__ BT_lo,
    void* __restrict__ C) {
  __shared__ unsigned int   As[GBM][GBK + 4];      // pad +4 u32
  __shared__ unsigned short Bh[GBN][GBK + 8];      // pad +8 ushort
  __shared__ unsigned short Bl[GBN][GBK + 8];
  const int tid = threadIdx.x;
  const int wv = tid >> 6, lane = tid & 63;
  const int col = lane & 15, quad = lane >> 4;
  const int wr = wv >> 2, wc = wv & 3;             // 4x4 waves over 64x64 tile
  const int bm0 = (blockIdx.x >> 4) * GBM;         // 16x16 = 256 blocks
  const int bn0 = (blockIdx.x & 15) * GBN;
  const int sr = tid >> 4;                         // staging row 0..63
  const int sc = (tid & 15) * 8;                   // staging col 0,8,...,120
  f32x4 acc = {0.f, 0.f, 0.f, 0.f};
  // prologue: chunk-0 loads into registers
  u32x4 ra0 = *(const u32x4*)(A + (size_t)(bm0 + sr) * K + sc);
  u32x4 ra1 = *(const u32x4*)(A + (size_t)(bm0 + sr) * K + sc + 4);
  bf16x8 rbh = *(const bf16x8*)(BT_hi + (size_t)(bn0 + sr) * K + sc);
  bf16x8 rbl = *(const bf16x8*)(BT_lo + (size_t)(bn0 + sr) * K + sc);
#pragma unroll 1
  for (int k0 = 0; k0 < K; k0 += GBK) {
    *(u32x4*)&As[sr][sc]     = ra0;
    *(u32x4*)&As[sr][sc + 4] = ra1;
    *(bf16x8*)&Bh[sr][sc] = rbh;
    *(bf16x8*)&Bl[sr][sc] = rbl;
    __syncthreads();
    if (k0 + GBK < K) {                            // prefetch next chunk
      ra0 = *(const u32x4*)(A + (size_t)(bm0 + sr) * K + k0 + GBK + sc);
      ra1 = *(const u32x4*)(A + (size_t)(bm0 + sr) * K + k0 + GBK + sc + 4);
      rbh = *(const bf16x8*)(BT_hi + (size_t)(bn0 + sr) * K + k0 + GBK + sc);
      rbl = *(const bf16x8*)(BT_lo + (size_t)(bn0 + sr) * K + k0 + GBK + sc);
    }
    // ---- compute: 4 sub-chunks of K=32 ----
#pragma unroll
    for (int s = 0; s < GBK; s += 32) {
      bf16x8 ahi, alo;
      u32x4 c0v = *(const u32x4*)&As[wr * 16 + col][s + quad * 8];
      u32x4 c1v = *(const u32x4*)&As[wr * 16 + col][s + quad * 8 + 4];
      unpack8v(c0v, c1v, ahi, alo);
      bf16x8 bh8 = *(const bf16x8*)&Bh[wc * 16 + col][s + quad * 8];
      bf16x8 bl8 = *(const bf16x8*)&Bl[wc * 16 + col][s + quad * 8];
      acc = __builtin_amdgcn_mfma_f32_16x16x32_bf16(ahi, bh8, acc, 0, 0, 0);
      acc = __builtin_amdgcn_mfma_f32_16x16x32_bf16(alo, bh8, acc, 0, 0, 0);
      acc = __builtin_amdgcn_mfma_f32_16x16x32_bf16(ahi, bl8, acc, 0, 0, 0);
    }
    __syncthreads();
  }
#pragma unroll
  for (int r = 0; r < 4; r++) {
    size_t idx = (size_t)(bm0 + wr * 16 + quad * 4 + r) * H_ + bn0 + wc * 16 + col;
    if (OUTMODE) ((unsigned int*)C)[idx] = packf(fmaxf(acc[r], 0.f));
    else         ((float*)C)[idx] = acc[r];
  }
}

// ---- K-split partial tile: NIT*32-u32 K chunk, A-loads issued up-front ----
template<int NIT>
__device__ __forceinline__ f32x4 mm_partN(
    const unsigned int* __restrict__ A, int am0, int k0,
    const unsigned short* __restrict__ BH, const unsigned short* __restrict__ BL,
    int bj0, int col, int quad) {
  const unsigned int*   ap = A  + (size_t)(am0 + col) * H_ + k0 + quad * 8;
  const unsigned short* bh = BH + (size_t)(bj0 + col) * H_ + k0 + quad * 8;
  const unsigned short* bl = BL + (size_t)(bj0 + col) * H_ + k0 + quad * 8;
  u32x4 ab[2 * NIT];
#pragma unroll
  for (int i = 0; i < NIT; i++) {
    ab[2 * i]     = *(const u32x4*)(ap + 32 * i);
    ab[2 * i + 1] = *(const u32x4*)(ap + 32 * i + 4);
  }
  f32x4 acc = {0.f, 0.f, 0.f, 0.f};
#pragma unroll
  for (int i = 0; i < NIT; i++) {
    bf16x8 ahi, alo;
    unpack8v(ab[2 * i], ab[2 * i + 1], ahi, alo);
    bf16x8 vh = *(const bf16x8*)(bh + 32 * i);
    bf16x8 vl = *(const bf16x8*)(bl + 32 * i);
    acc = __builtin_amdgcn_mfma_f32_16x16x32_bf16(ahi, vh, acc, 0, 0, 0);
    acc = __builtin_amdgcn_mfma_f32_16x16x32_bf16(alo, vh, acc, 0, 0, 0);
    acc = __builtin_amdgcn_mfma_f32_16x16x32_bf16(ahi, vl, acc, 0, 0, 0);
  }
  return acc;
}
// full-K tile (for final y GEMM)
__device__ __forceinline__ f32x4 mm_tile_pf(
    const unsigned int* __restrict__ A, int am0,
    const unsigned short* __restrict__ BH, const unsigned short* __restrict__ BL,
    int bj0, f32x4 acc, int col, int quad) {
#pragma unroll 1
  for (int kk = 0; kk < H_; kk += 256) {
    f32x4 p = mm_partN<8>(A, am0, kk, BH, BL, bj0, col, quad);
    acc[0] += p[0]; acc[1] += p[1]; acc[2] += p[2]; acc[3] += p[3];
  }
  return acc;
}

// ---------- recurrent: 64 blocks x 1024 thr; 16-col slices (r5 verified) ----------
// r12: block-local only changes — parallel BN (one-pass shuffle) +
//      parity-split attention walk (halved dependent chain). No sync changes.
__global__ void __launch_bounds__(NTHR) recurrent(
    const unsigned short* __restrict__ WhT_hi, const unsigned short* __restrict__ WhT_lo,
    const unsigned short* __restrict__ WhoT_hi, const unsigned short* __restrict__ WhoT_lo,
    const unsigned short* __restrict__ WoT_hi, const unsigned short* __restrict__ WoT_lo,
    const float* __restrict__ ZC,
    unsigned int* __restrict__ hq,
    unsigned int* __restrict__ hc,
    unsigned int* __restrict__ Opub,
    float* __restrict__ hist_loc,     // [NBLK][T][B][NCOL] block-private f32
    float* __restrict__ dots_g,       // [T][B][T] atomicAdd fan-in
    const float* __restrict__ par,
    void* __restrict__ y_out,
    int* __restrict__ cnt,
    const int* __restrict__ flag)
{
  __shared__ f32x4 red[16][64];               // 16 KB: per-wave partial accs
  __shared__ float lds_hs[B_][NCOL + 1];
  __shared__ float lds_dt[B_][T_];
  __shared__ float lds_mu[NCOL], lds_sc[NCOL], lds_bb[NCOL];
  __shared__ float att_p[B_ * NCOL];          // 2 KB: odd-parity attention partials

  const int tid = threadIdx.x, wg = blockIdx.x;
  const int wv = tid >> 6, lane = tid & 63;
  const int col = lane & 15, quad = lane >> 4;
  const int j0 = wg * NCOL;
  const int tile = wv & 1, kp = wv >> 1;      // 2 row-tiles x 8 K-parts (128 u32 each)
  const int am0 = tile * 16;
  const int k0 = kp * 128;
  const float lam = par[0], eta = par[1];
  const float lam2 = lam * lam;
  const bool isf32 = flag[0] != 0;
  float* hl = hist_loc + (size_t)wg * (T_ * B_ * NCOL);

  // zero hc[0] own cols + dots slice
  for (int d = tid; d < B_ * NCOL; d += NTHR) {
    int b = d >> 4, c = d & 15;
    astu(hc + (size_t)b * H_ + j0 + c, 0u);
  }
  for (int i = tid; i < T_ * B_ * T_ / NBLK; i += NTHR)
    astf(dots_g + (size_t)wg * (T_ * B_ * T_ / NBLK) + i, 0.f);
  rendezvous(cnt, 0);

  int slot = 1;
  for (int t = 0; t < T_; ++t) {
    const float* zb = ZC + (size_t)t * B_ * H_;
    const unsigned int* hcur = hc + (size_t)t * B_ * H_;
    unsigned int* hqt = hq + (size_t)t * B_ * H_;
    float* dt = dots_g + (size_t)t * B_ * T_;
    // ---- stage 1: h_t = relu(zc + h_cur @ W_h) — K-split across 16 waves ----
    red[wv][lane] = mm_partN<4>(hcur, am0, k0, WhT_hi, WhT_lo, j0, col, quad);
    __syncthreads();
    if (wv < 2) {
      int a0 = wv * 16;
      f32x4 s = red[wv][lane];
#pragma unroll
      for (int k = 1; k < 8; k++) {
        f32x4 p = red[wv + 2 * k][lane];
        s[0] += p[0]; s[1] += p[1]; s[2] += p[2]; s[3] += p[3];
      }
#pragma unroll
      for (int r = 0; r < 4; r++) {
        float v = zb[(size_t)(a0 + quad * 4 + r) * H_ + j0 + col] + s[r];
        v = fmaxf(v, 0.f);
        int m = a0 + quad * 4 + r;
        hl[((size_t)t * B_ + m) * NCOL + col] = v;
        astu(hqt + (size_t)m * H_ + j0 + col, packf(v));
      }
    }
    __syncthreads();
    // ---- partial dots over own cols -> atomicAdd (batch rotated by wg) ----
    for (int d = tid; d < B_ * (t + 1); d += NTHR) {
      int b = ((d / (t + 1)) + wg) & (B_ - 1);
      int s = d % (t + 1);
      const f32x4* p = (const f32x4*)(hl + ((size_t)t * B_ + b) * NCOL);
      const f32x4* q = (const f32x4*)(hl + ((size_t)s * B_ + b) * NCOL);
      float sum = 0.f;
#pragma unroll
      for (int i = 0; i < 4; i++) {
        f32x4 a = p[i], c = q[i];
        sum += a[0] * c[0] + a[1] * c[1] + a[2] * c[2] + a[3] * c[3];
      }
      aaddf(dt + (size_t)b * T_ + s, sum);
    }
    rendezvous(cnt, slot++);
    // ---- dots[t] -> LDS ----
    for (int d = tid; d < B_ * (t + 1); d += NTHR) {
      int b = d / (t + 1), s = d - b * (t + 1);
      lds_dt[b][s] = dt[(size_t)b * T_ + s];
    }
    // ---- hs GEMM: h_t @ W_h + zc — K-split ----
    red[wv][lane] = mm_partN<4>(hqt, am0, k0, WhT_hi, WhT_lo, j0, col, quad);
    __syncthreads();
    if (wv < 2) {
      int a0 = wv * 16;
      f32x4 s = red[wv][lane];
#pragma unroll
      for (int k = 1; k < 8; k++) {
        f32x4 p = red[wv + 2 * k][lane];
        s[0] += p[0]; s[1] += p[1]; s[2] += p[2]; s[3] += p[3];
      }
#pragma unroll
      for (int r = 0; r < 4; r++)
        lds_hs[a0 + quad * 4 + r][col] =
            zb[(size_t)(a0 + quad * 4 + r) * H_ + j0 + col] + s[r];
    }
    __syncthreads();
    // ---- attention: += eta * sum_s lam^(t-s) dots[b][s] * hl[s][b][c] ----
    // parity-split: thread pair (d, d+512) handles even/odd (t-s) offsets.
    {
      int d = tid & 511, j = tid >> 9;          // j=0: s=t,t-2,..; j=1: s=t-1,t-3,..
      int b = d >> 4, c = d & 15;
      float a = 0.f, w = eta * (j ? lam : 1.f);
      const float* hb = hl + (size_t)b * NCOL + c;
      for (int s = t - j; s >= 0; s -= 2) {
        a += w * lds_dt[b][s] * hb[(size_t)s * B_ * NCOL];
        w *= lam2;
      }
      if (j) att_p[d] = a;
      __syncthreads();
      if (!j) lds_hs[b][c] += a + att_p[d];
    }
    __syncthreads();
    // ---- batch-norm: one-pass sum/sumsq, 32 lanes per column, shuffle reduce ----
    if (tid < 512) {
      int c = tid >> 5, i = tid & 31;           // 16 cols x 32 batches
      float x = lds_hs[i][c];
      float s = x, q = x * x;
#pragma unroll
      for (int o = 1; o < 32; o <<= 1) { s += __shfl_xor(s, o); q += __shfl_xor(q, o); }
      if (i == 0) {
        float mu = s * (1.f / B_);
        float var = fmaxf(q * (1.f / B_) - mu * mu, 0.f);
        float sig = sqrtf(var);
        lds_mu[c] = mu;
        lds_sc[c] = par[2 + j0 + c] / sig;
        lds_bb[c] = par[2 + H_ + j0 + c];
      }
    }
    __syncthreads();
    // ---- apply + publish hc[t+1] own cols ----
    for (int d = tid; d < B_ * NCOL; d += NTHR) {
      int b = d >> 4, c = d & 15;
      float v = (lds_hs[b][c] - lds_mu[c]) * lds_sc[c] + lds_bb[c];
      astu(hc + (size_t)(t + 1) * B_ * H_ + (size_t)b * H_ + j0 + c, packf(fmaxf(v, 0.f)));
    }
    rendezvous(cnt, slot++);
  }
  // ---- o = relu(hc[T] @ W_ho), own cols — K-split ----
  {
    const unsigned int* hfin = hc + (size_t)T_ * B_ * H_;
    red[wv][lane] = mm_partN<4>(hfin, am0, k0, WhoT_hi, WhoT_lo, j0, col, quad);
    __syncthreads();
    if (wv < 2) {
      int a0 = wv * 16;
      f32x4 s = red[wv][lane];
#pragma unroll
      for (int k = 1; k < 8; k++) {
        f32x4 p = red[wv + 2 * k][lane];
        s[0] += p[0]; s[1] += p[1]; s[2] += p[2]; s[3] += p[3];
      }
#pragma unroll
      for (int r = 0; r < 4; r++) {
        float v = fmaxf(s[r], 0.f);
        astu(Opub + (size_t)(a0 + quad * 4 + r) * H_ + j0 + col, packf(v));
      }
    }
  }
  rendezvous(cnt, slot++);
  // ---- y = relu(o @ W_o): 32 tiles on blocks 0..1 (full-K) ----
  if (wg < 2) {
    int id = wg * 16 + wv;            // 0..31
    int bt2 = id & 1, jt2 = id >> 1;  // jt2 0..15
    f32x4 acc = {0.f, 0.f, 0.f, 0.f};
    acc = mm_tile_pf(Opub, bt2 * 16, WoT_hi, WoT_lo, jt2 * 16, acc, col, quad);
#pragma unroll
    for (int r = 0; r < 4; r++) {
      float v = fmaxf(acc[r], 0.f);
      size_t idx = (size_t)(bt2 * 16 + quad * 4 + r) * NOUT_ + jt2 * 16 + col;
      if (isf32) ((float*)y_out)[idx] = v;
      else       ((unsigned short*)y_out)[idx] = f2bf(v);
    }
  }
}

extern "C" void kernel_launch(void* const* d_in, const int* in_sizes, int n_in,
                              void* d_out, int out_size, void* d_ws, size_t ws_size,
                              hipStream_t stream) {
  const void* x_in = d_in[0];
  const void* W_i  = d_in[1];
  const void* W_z  = d_in[2];
  const void* W_c  = d_in[3];
  const void* W_h  = d_in[4];
  const void* W_ho = d_in[5];
  const void* W_o  = d_in[6];
  const void* lam  = d_in[7];
  const void* eta  = d_in[8];
  const void* g    = d_in[9];
  const void* bb   = d_in[10];

  char* wsp = (char*)d_ws;
  size_t off = 0;
  auto alloc = [&](size_t bytes) {
    void* p = wsp + off;
    off += (bytes + 255) & ~(size_t)255;
    return p;
  };
  int*            flag    = (int*)alloc(16);
  int*            cnt     = (int*)alloc(NSLOT * 4);
  float*          par     = (float*)alloc((2 + 2 * H_) * 4);
  unsigned int*   X_pk    = (unsigned int*)alloc((size_t)T_ * B_ * NIN_ * 4);
  unsigned short* WiT_hi  = (unsigned short*)alloc((size_t)NIN_ * H_ * 2);
  unsigned short* WiT_lo  = (unsigned short*)alloc((size_t)NIN_ * H_ * 2);
  unsigned short* WzT_hi  = (unsigned short*)alloc((size_t)H_ * H_ * 2);
  unsigned short* WzT_lo  = (unsigned short*)alloc((size_t)H_ * H_ * 2);
  unsigned short* WcT_hi  = (unsigned short*)alloc((size_t)H_ * H_ * 2);
  unsigned short* WcT_lo  = (unsigned short*)alloc((size_t)H_ * H_ * 2);
  unsigned short* WhT_hi  = (unsigned short*)alloc((size_t)H_ * H_ * 2);
  unsigned short* WhT_lo  = (unsigned short*)alloc((size_t)H_ * H_ * 2);
  unsigned short* WhoT_hi = (unsigned short*)alloc((size_t)H_ * H_ * 2);
  unsigned short* WhoT_lo = (unsigned short*)alloc((size_t)H_ * H_ * 2);
  unsigned short* WoT_hi  = (unsigned short*)alloc((size_t)H_ * NOUT_ * 2);
  unsigned short* WoT_lo  = (unsigned short*)alloc((size_t)H_ * NOUT_ * 2);
  unsigned int*   S_pk    = (unsigned int*)alloc((size_t)T_ * B_ * H_ * 4);
  unsigned int*   Z_pk    = (unsigned int*)alloc((size_t)T_ * B_ * H_ * 4);
  float*          ZC      = (float*)alloc((size_t)T_ * B_ * H_ * 4);
  unsigned int*   hq      = (unsigned int*)alloc((size_t)T_ * B_ * H_ * 4);
  unsigned int*   hc      = (unsigned int*)alloc((size_t)(T_ + 1) * B_ * H_ * 4);
  unsigned int*   Opub    = (unsigned int*)alloc((size_t)B_ * H_ * 4);
  float*          histloc = (float*)alloc((size_t)NBLK * T_ * B_ * NCOL * 4);
  float*          dots_g  = (float*)alloc((size_t)T_ * B_ * T_ * 4);
  (void)ws_size; (void)in_sizes; (void)n_in; (void)out_size;

  // 1. detect dtype + zero counters
  init_detect<<<1, 256, 0, stream>>>((const unsigned short*)x_in, flag, cnt);

  // 2. fused prep: pack x | params | all 6 transposes (one launch)
  prep_all<<<PACKB + 4 + 4864, 256, 0, stream>>>(
      x_in, X_pk, lam, eta, g, bb, par,
      W_i, WiT_hi, WiT_lo, W_z, WzT_hi, WzT_lo, W_c, WcT_hi, WcT_lo,
      W_h, WhT_hi, WhT_lo, W_ho, WhoT_hi, WhoT_lo, W_o, WoT_hi, WoT_lo,
      flag);

  // 3. phase A (LDS-tiled 64x64 + reg-prefetch): S, Z, ZC
  gemmT<NIN_, 1><<<256, 1024, 0, stream>>>(X_pk, WiT_hi, WiT_lo, S_pk);
  gemmT<H_,   1><<<256, 1024, 0, stream>>>(S_pk, WzT_hi, WzT_lo, Z_pk);
  gemmT<H_,   0><<<256, 1024, 0, stream>>>(Z_pk, WcT_hi, WcT_lo, ZC);

  // 4. phase B: recurrence + readout, 64-block 16-col K-split GEMMs (r5 verified)
  recurrent<<<NBLK, NTHR, 0, stream>>>(WhT_hi, WhT_lo, WhoT_hi, WhoT_lo, WoT_hi, WoT_lo,
                                       ZC, hq, hc, Opub, histloc, dots_g,
                                       par, d_out, cnt, flag);
}

// Round 13
// 714.710 us; speedup vs baseline: 1.0279x; 1.0279x over previous
//
#include <hip/hip_runtime.h>
#include <hip/hip_bf16.h>

#define T_   32
#define B_   32
#define NIN_ 512
#define H_   1024
#define NOUT_ 256
#define NBLK 64          // 64 blocks x 16 cols (verified best: r5, 585us)
#define NTHR 1024
#define NCOL 16
#define NSLOT 80
#define PACKB 128        // prep_all: blocks 0..PACKB-1 pack x
#define GBM 64           // gemmT tile (r9-verified) + reg-prefetch dbuf
#define GBN 64
#define GBK 128

typedef short bf16x8 __attribute__((ext_vector_type(8)));
typedef float f32x4  __attribute__((ext_vector_type(4)));
typedef unsigned int u32x4 __attribute__((ext_vector_type(4)));

__device__ __forceinline__ float bf2f(unsigned short u) {
  union { unsigned int i; float f; } x; x.i = ((unsigned int)u) << 16; return x.f;
}
__device__ __forceinline__ unsigned short f2bf(float f) {
  __hip_bfloat16 h = __float2bfloat16(f);
  return *reinterpret_cast<unsigned short*>(&h);
}
__device__ __forceinline__ unsigned int packf(float v) {
  unsigned short h = f2bf(v);
  unsigned short l = f2bf(v - bf2f(h));
  return ((unsigned int)h << 16) | l;
}
__device__ __forceinline__ void unpack8v(u32x4 a, u32x4 b, bf16x8& hi, bf16x8& lo) {
  unsigned int t[8] = {a[0], a[1], a[2], a[3], b[0], b[1], b[2], b[3]};
  union { bf16x8 v; unsigned int u[4]; } H, L;
#pragma unroll
  for (int j = 0; j < 4; j++) {
    unsigned int e = t[2 * j], o = t[2 * j + 1];
    H.u[j] = (o & 0xFFFF0000u) | (e >> 16);
    L.u[j] = (o << 16) | (e & 0xFFFFu);
  }
  hi = H.v; lo = L.v;
}

// ---- publish primitives: relaxed agent-scope atomics ----
__device__ __forceinline__ void astu(unsigned int* p, unsigned int v) {
  __hip_atomic_store(p, v, __ATOMIC_RELAXED, __HIP_MEMORY_SCOPE_AGENT);
}
__device__ __forceinline__ void astf(float* p, float v) {
  __hip_atomic_store(p, v, __ATOMIC_RELAXED, __HIP_MEMORY_SCOPE_AGENT);
}
__device__ __forceinline__ void aaddf(float* p, float v) {
  __hip_atomic_fetch_add(p, v, __ATOMIC_RELAXED, __HIP_MEMORY_SCOPE_AGENT);
}

// ---- rendezvous: fresh slot; relaxed arrival + relaxed spin (r0/r5 verified) ----
__device__ __forceinline__ void rendezvous(int* cnt, int slot) {
  __syncthreads();
  if (threadIdx.x == 0) {
    __hip_atomic_fetch_add(&cnt[slot], 1, __ATOMIC_RELAXED, __HIP_MEMORY_SCOPE_AGENT);
    while (__hip_atomic_load(&cnt[slot], __ATOMIC_RELAXED, __HIP_MEMORY_SCOPE_AGENT) < NBLK)
      __builtin_amdgcn_s_sleep(1);
    __atomic_signal_fence(__ATOMIC_ACQUIRE);
  }
  __syncthreads();
}

// ---------- dtype detect + counter init ----------
__global__ void init_detect(const unsigned short* __restrict__ x_raw,
                            int* __restrict__ flag, int* __restrict__ cnt) {
  __shared__ int bad;
  if (threadIdx.x == 0) bad = 0;
  __syncthreads();
  int c = 0;
  for (int i = threadIdx.x; i < 2048; i += 256) {
    float v = bf2f(x_raw[i]);
    if (!(fabsf(v) < 1e9f)) c++;
  }
  if (c) atomicAdd(&bad, 1);
  __syncthreads();
  if (threadIdx.x == 0) flag[0] = bad ? 1 : 0;  // 1 = inputs are f32
  for (int i = threadIdx.x; i < NSLOT; i += 256)
    __hip_atomic_store(&cnt[i], 0, __ATOMIC_RELAXED, __HIP_MEMORY_SCOPE_AGENT);
}

// ---------- fused prep: pack x | params | 6x transpose+split (one launch) ----------
__global__ void prep_all(
    const void* __restrict__ x_in, unsigned int* __restrict__ X_pk,
    const void* lam, const void* eta, const void* g, const void* b,
    float* __restrict__ par,
    const void* __restrict__ W_i,  unsigned short* __restrict__ WiT_hi,  unsigned short* __restrict__ WiT_lo,
    const void* __restrict__ W_z,  unsigned short* __restrict__ WzT_hi,  unsigned short* __restrict__ WzT_lo,
    const void* __restrict__ W_c,  unsigned short* __restrict__ WcT_hi,  unsigned short* __restrict__ WcT_lo,
    const void* __restrict__ W_h,  unsigned short* __restrict__ WhT_hi,  unsigned short* __restrict__ WhT_lo,
    const void* __restrict__ W_ho, unsigned short* __restrict__ WhoT_hi, unsigned short* __restrict__ WhoT_lo,
    const void* __restrict__ W_o,  unsigned short* __restrict__ WoT_hi,  unsigned short* __restrict__ WoT_lo,
    const int* __restrict__ flag)
{
  const bool isf32 = flag[0] != 0;
  int blk = blockIdx.x;
  if (blk < PACKB) {                      // ---- x -> relu+pack ----
    const int n = T_ * B_ * NIN_;
    for (int i = blk * 256 + threadIdx.x; i < n; i += PACKB * 256) {
      float v = isf32 ? ((const float*)x_in)[i] : bf2f(((const unsigned short*)x_in)[i]);
      X_pk[i] = packf(fmaxf(v, 0.f));
    }
    return;
  }
  blk -= PACKB;
  if (blk < 4) {                          // ---- params ----
    int t = blk * 256 + threadIdx.x;
    if (t == 0) {
      par[0] = isf32 ? ((const float*)lam)[0] : bf2f(((const unsigned short*)lam)[0]);
      par[1] = isf32 ? ((const float*)eta)[0] : bf2f(((const unsigned short*)eta)[0]);
    }
    if (t < H_) {
      par[2 + t]      = isf32 ? ((const float*)g)[t] : bf2f(((const unsigned short*)g)[t]);
      par[2 + H_ + t] = isf32 ? ((const float*)b)[t] : bf2f(((const unsigned short*)b)[t]);
    }
    return;
  }
  blk -= 4;                               // ---- transpose + hi/lo split ----
  const void* src; unsigned short *dhi, *dlo; int R, C;
  int tb = blk;
  if (tb < 512)       { src = W_i;  dhi = WiT_hi;  dlo = WiT_lo;  R = NIN_; C = H_; }
  else if (tb < 1536) { tb -= 512;  src = W_z;  dhi = WzT_hi;  dlo = WzT_lo;  R = H_; C = H_; }
  else if (tb < 2560) { tb -= 1536; src = W_c;  dhi = WcT_hi;  dlo = WcT_lo;  R = H_; C = H_; }
  else if (tb < 3584) { tb -= 2560; src = W_h;  dhi = WhT_hi;  dlo = WhT_lo;  R = H_; C = H_; }
  else if (tb < 4608) { tb -= 3584; src = W_ho; dhi = WhoT_hi; dlo = WhoT_lo; R = H_; C = H_; }
  else                { tb -= 4608; src = W_o;  dhi = WoT_hi;  dlo = WoT_lo;  R = H_; C = NOUT_; }
  __shared__ unsigned short thi[32][33], tlo[32][33];
  int ncx = C >> 5;
  int c0 = (tb % ncx) * 32, r0 = (tb / ncx) * 32;
  int tx = threadIdx.x & 31, ty = threadIdx.x >> 5;
  for (int i = ty; i < 32; i += 8) {
    size_t idx = (size_t)(r0 + i) * C + c0 + tx;
    float v = isf32 ? ((const float*)src)[idx] : bf2f(((const unsigned short*)src)[idx]);
    unsigned short h = f2bf(v);
    thi[i][tx] = h;
    tlo[i][tx] = f2bf(v - bf2f(h));
  }
  __syncthreads();
  for (int i = ty; i < 32; i += 8) {
    dhi[(size_t)(c0 + i) * R + r0 + tx] = thi[tx][i];
    dlo[(size_t)(c0 + i) * R + r0 + tx] = tlo[tx][i];
  }
}

// ---------- phase-A GEMM, LDS-tiled 64x64 (r9-verified) + reg-prefetch dbuf ----------
// Loads for chunk k+1 issue right after the staging barrier and complete under
// the MFMA/LDS compute of chunk k (G15) — removes per-chunk global latency.
template<int K, int OUTMODE>
__global__ void __launch_bounds__(1024) gemmT(
    const unsigned int* __restrict__ A,
    const unsigned short* __restrict__ BT_hi,
    const unsigned short* __restrict__ BT_lo,
    void* __restrict__ C) {
  __shared__ unsigned int   As[GBM][GBK + 4];      // pad +4 u32
  __shared__ unsigned short Bh[GBN][GBK + 8];      // pad +8 ushort
  __shared__ unsigned short Bl[GBN][GBK + 8];
  const int tid = threadIdx.x;
  const int wv = tid >> 6, lane = tid & 63;
  const int col = lane & 15, quad = lane >> 4;
  const int wr = wv >> 2, wc = wv & 3;             // 4x4 waves over 64x64 tile
  const int bm0 = (blockIdx.x >> 4) * GBM;         // 16x16 = 256 blocks
  const int bn0 = (blockIdx.x & 15) * GBN;
  const int sr = tid >> 4;                         // staging row 0..63
  const int sc = (tid & 15) * 8;                   // staging col 0,8,...,120
  f32x4 acc = {0.f, 0.f, 0.f, 0.f};
  // prologue: chunk-0 loads into registers
  u32x4 ra0 = *(const u32x4*)(A + (size_t)(bm0 + sr) * K + sc);
  u32x4 ra1 = *(const u32x4*)(A + (size_t)(bm0 + sr) * K + sc + 4);
  bf16x8 rbh = *(const bf16x8*)(BT_hi + (size_t)(bn0 + sr) * K + sc);
  bf16x8 rbl = *(const bf16x8*)(BT_lo + (size_t)(bn0 + sr) * K + sc);
#pragma unroll 1
  for (int k0 = 0; k0 < K; k0 += GBK) {
    *(u32x4*)&As[sr][sc]     = ra0;
    *(u32x4*)&As[sr][sc + 4] = ra1;
    *(bf16x8*)&Bh[sr][sc] = rbh;
    *(bf16x8*)&Bl[sr][sc] = rbl;
    __syncthreads();
    if (k0 + GBK < K) {                            // prefetch next chunk
      ra0 = *(const u32x4*)(A + (size_t)(bm0 + sr) * K + k0 + GBK + sc);
      ra1 = *(const u32x4*)(A + (size_t)(bm0 + sr) * K + k0 + GBK + sc + 4);
      rbh = *(const bf16x8*)(BT_hi + (size_t)(bn0 + sr) * K + k0 + GBK + sc);
      rbl = *(const bf16x8*)(BT_lo + (size_t)(bn0 + sr) * K + k0 + GBK + sc);
    }
    // ---- compute: 4 sub-chunks of K=32 ----
#pragma unroll
    for (int s = 0; s < GBK; s += 32) {
      bf16x8 ahi, alo;
      u32x4 c0v = *(const u32x4*)&As[wr * 16 + col][s + quad * 8];
      u32x4 c1v = *(const u32x4*)&As[wr * 16 + col][s + quad * 8 + 4];
      unpack8v(c0v, c1v, ahi, alo);
      bf16x8 bh8 = *(const bf16x8*)&Bh[wc * 16 + col][s + quad * 8];
      bf16x8 bl8 = *(const bf16x8*)&Bl[wc * 16 + col][s + quad * 8];
      acc = __builtin_amdgcn_mfma_f32_16x16x32_bf16(ahi, bh8, acc, 0, 0, 0);
      acc = __builtin_amdgcn_mfma_f32_16x16x32_bf16(alo, bh8, acc, 0, 0, 0);
      acc = __builtin_amdgcn_mfma_f32_16x16x32_bf16(ahi, bl8, acc, 0, 0, 0);
    }
    __syncthreads();
  }
#pragma unroll
  for (int r = 0; r < 4; r++) {
    size_t idx = (size_t)(bm0 + wr * 16 + quad * 4 + r) * H_ + bn0 + wc * 16 + col;
    if (OUTMODE) ((unsigned int*)C)[idx] = packf(fmaxf(acc[r], 0.f));
    else         ((float*)C)[idx] = acc[r];
  }
}

// ---- K-split partial tile: NIT*32-u32 K chunk, A-loads issued up-front ----
template<int NIT>
__device__ __forceinline__ f32x4 mm_partN(
    const unsigned int* __restrict__ A, int am0, int k0,
    const unsigned short* __restrict__ BH, const unsigned short* __restrict__ BL,
    int bj0, int col, int quad) {
  const unsigned int*   ap = A  + (size_t)(am0 + col) * H_ + k0 + quad * 8;
  const unsigned short* bh = BH + (size_t)(bj0 + col) * H_ + k0 + quad * 8;
  const unsigned short* bl = BL + (size_t)(bj0 + col) * H_ + k0 + quad * 8;
  u32x4 ab[2 * NIT];
#pragma unroll
  for (int i = 0; i < NIT; i++) {
    ab[2 * i]     = *(const u32x4*)(ap + 32 * i);
    ab[2 * i + 1] = *(const u32x4*)(ap + 32 * i + 4);
  }
  f32x4 acc = {0.f, 0.f, 0.f, 0.f};
#pragma unroll
  for (int i = 0; i < NIT; i++) {
    bf16x8 ahi, alo;
    unpack8v(ab[2 * i], ab[2 * i + 1], ahi, alo);
    bf16x8 vh = *(const bf16x8*)(bh + 32 * i);
    bf16x8 vl = *(const bf16x8*)(bl + 32 * i);
    acc = __builtin_amdgcn_mfma_f32_16x16x32_bf16(ahi, vh, acc, 0, 0, 0);
    acc = __builtin_amdgcn_mfma_f32_16x16x32_bf16(alo, vh, acc, 0, 0, 0);
    acc = __builtin_amdgcn_mfma_f32_16x16x32_bf16(ahi, vl, acc, 0, 0, 0);
  }
  return acc;
}
// full-K tile (for final y GEMM)
__device__ __forceinline__ f32x4 mm_tile_pf(
    const unsigned int* __restrict__ A, int am0,
    const unsigned short* __restrict__ BH, const unsigned short* __restrict__ BL,
    int bj0, f32x4 acc, int col, int quad) {
#pragma unroll 1
  for (int kk = 0; kk < H_; kk += 256) {
    f32x4 p = mm_partN<8>(A, am0, kk, BH, BL, bj0, col, quad);
    acc[0] += p[0]; acc[1] += p[1]; acc[2] += p[2]; acc[3] += p[3];
  }
  return acc;
}

// ---------- recurrent: 64 blocks x 1024 thr; 16-col slices (r5 verified) ----------
__global__ void __launch_bounds__(NTHR) recurrent(
    const unsigned short* __restrict__ WhT_hi, const unsigned short* __restrict__ WhT_lo,
    const unsigned short* __restrict__ WhoT_hi, const unsigned short* __restrict__ WhoT_lo,
    const unsigned short* __restrict__ WoT_hi, const unsigned short* __restrict__ WoT_lo,
    const float* __restrict__ ZC,
    unsigned int* __restrict__ hq,
    unsigned int* __restrict__ hc,
    unsigned int* __restrict__ Opub,
    float* __restrict__ hist_loc,     // [NBLK][T][B][NCOL] block-private f32
    float* __restrict__ dots_g,       // [T][B][T] atomicAdd fan-in
    const float* __restrict__ par,
    void* __restrict__ y_out,
    int* __restrict__ cnt,
    const int* __restrict__ flag)
{
  __shared__ f32x4 red[16][64];               // 16 KB: per-wave partial accs
  __shared__ float lds_hs[B_][NCOL + 1];
  __shared__ float lds_dt[B_][T_];
  __shared__ float lds_mu[NCOL], lds_sc[NCOL], lds_bb[NCOL];

  const int tid = threadIdx.x, wg = blockIdx.x;
  const int wv = tid >> 6, lane = tid & 63;
  const int col = lane & 15, quad = lane >> 4;
  const int j0 = wg * NCOL;
  const int tile = wv & 1, kp = wv >> 1;      // 2 row-tiles x 8 K-parts (128 u32 each)
  const int am0 = tile * 16;
  const int k0 = kp * 128;
  const float lam = par[0], eta = par[1];
  const bool isf32 = flag[0] != 0;
  float* hl = hist_loc + (size_t)wg * (T_ * B_ * NCOL);

  // zero hc[0] own cols + dots slice
  for (int d = tid; d < B_ * NCOL; d += NTHR) {
    int b = d >> 4, c = d & 15;
    astu(hc + (size_t)b * H_ + j0 + c, 0u);
  }
  for (int i = tid; i < T_ * B_ * T_ / NBLK; i += NTHR)
    astf(dots_g + (size_t)wg * (T_ * B_ * T_ / NBLK) + i, 0.f);
  rendezvous(cnt, 0);

  int slot = 1;
  for (int t = 0; t < T_; ++t) {
    const float* zb = ZC + (size_t)t * B_ * H_;
    const unsigned int* hcur = hc + (size_t)t * B_ * H_;
    unsigned int* hqt = hq + (size_t)t * B_ * H_;
    float* dt = dots_g + (size_t)t * B_ * T_;
    // ---- stage 1: h_t = relu(zc + h_cur @ W_h) — K-split across 16 waves ----
    red[wv][lane] = mm_partN<4>(hcur, am0, k0, WhT_hi, WhT_lo, j0, col, quad);
    __syncthreads();
    if (wv < 2) {
      int a0 = wv * 16;
      f32x4 s = red[wv][lane];
#pragma unroll
      for (int k = 1; k < 8; k++) {
        f32x4 p = red[wv + 2 * k][lane];
        s[0] += p[0]; s[1] += p[1]; s[2] += p[2]; s[3] += p[3];
      }
#pragma unroll
      for (int r = 0; r < 4; r++) {
        float v = zb[(size_t)(a0 + quad * 4 + r) * H_ + j0 + col] + s[r];
        v = fmaxf(v, 0.f);
        int m = a0 + quad * 4 + r;
        hl[((size_t)t * B_ + m) * NCOL + col] = v;
        astu(hqt + (size_t)m * H_ + j0 + col, packf(v));
      }
    }
    __syncthreads();
    // ---- partial dots over own cols -> atomicAdd (batch rotated by wg) ----
    for (int d = tid; d < B_ * (t + 1); d += NTHR) {
      int b = ((d / (t + 1)) + wg) & (B_ - 1);
      int s = d % (t + 1);
      const f32x4* p = (const f32x4*)(hl + ((size_t)t * B_ + b) * NCOL);
      const f32x4* q = (const f32x4*)(hl + ((size_t)s * B_ + b) * NCOL);
      float sum = 0.f;
#pragma unroll
      for (int i = 0; i < 4; i++) {
        f32x4 a = p[i], c = q[i];
        sum += a[0] * c[0] + a[1] * c[1] + a[2] * c[2] + a[3] * c[3];
      }
      aaddf(dt + (size_t)b * T_ + s, sum);
    }
    rendezvous(cnt, slot++);
    // ---- dots[t] -> LDS ----
    for (int d = tid; d < B_ * (t + 1); d += NTHR) {
      int b = d / (t + 1), s = d - b * (t + 1);
      lds_dt[b][s] = dt[(size_t)b * T_ + s];
    }
    // ---- hs GEMM: h_t @ W_h + zc — K-split ----
    red[wv][lane] = mm_partN<4>(hqt, am0, k0, WhT_hi, WhT_lo, j0, col, quad);
    __syncthreads();
    if (wv < 2) {
      int a0 = wv * 16;
      f32x4 s = red[wv][lane];
#pragma unroll
      for (int k = 1; k < 8; k++) {
        f32x4 p = red[wv + 2 * k][lane];
        s[0] += p[0]; s[1] += p[1]; s[2] += p[2]; s[3] += p[3];
      }
#pragma unroll
      for (int r = 0; r < 4; r++)
        lds_hs[a0 + quad * 4 + r][col] =
            zb[(size_t)(a0 + quad * 4 + r) * H_ + j0 + col] + s[r];
    }
    __syncthreads();
    // ---- attention: += eta * sum_s lam^(t-s) dots[b][s] * hl[s][b][c] ----
    for (int d = tid; d < B_ * NCOL; d += NTHR) {
      int b = d >> 4, c = d & 15;
      float a = 0.f, w = eta;
      const float* hb = hl + (size_t)b * NCOL + c;
      for (int s = t; s >= 0; --s) {
        a += w * lds_dt[b][s] * hb[(size_t)s * B_ * NCOL];
        w *= lam;
      }
      lds_hs[b][c] += a;
    }
    __syncthreads();
    // ---- batch-norm (block-local, full B per column) ----
    if (tid < NCOL) {
      int c = tid;
      float sum = 0.f;
#pragma unroll
      for (int b = 0; b < B_; b++) sum += lds_hs[b][c];
      float mu = sum * (1.f / B_);
      float sq = 0.f;
#pragma unroll
      for (int b = 0; b < B_; b++) {
        float dd = lds_hs[b][c] - mu;
        sq += dd * dd;
      }
      float sig = sqrtf(sq * (1.f / B_));
      lds_mu[c] = mu;
      lds_sc[c] = par[2 + j0 + c] / sig;
      lds_bb[c] = par[2 + H_ + j0 + c];
    }
    __syncthreads();
    // ---- apply + publish hc[t+1] own cols ----
    for (int d = tid; d < B_ * NCOL; d += NTHR) {
      int b = d >> 4, c = d & 15;
      float v = (lds_hs[b][c] - lds_mu[c]) * lds_sc[c] + lds_bb[c];
      astu(hc + (size_t)(t + 1) * B_ * H_ + (size_t)b * H_ + j0 + c, packf(fmaxf(v, 0.f)));
    }
    rendezvous(cnt, slot++);
  }
  // ---- o = relu(hc[T] @ W_ho), own cols — K-split ----
  {
    const unsigned int* hfin = hc + (size_t)T_ * B_ * H_;
    red[wv][lane] = mm_partN<4>(hfin, am0, k0, WhoT_hi, WhoT_lo, j0, col, quad);
    __syncthreads();
    if (wv < 2) {
      int a0 = wv * 16;
      f32x4 s = red[wv][lane];
#pragma unroll
      for (int k = 1; k < 8; k++) {
        f32x4 p = red[wv + 2 * k][lane];
        s[0] += p[0]; s[1] += p[1]; s[2] += p[2]; s[3] += p[3];
      }
#pragma unroll
      for (int r = 0; r < 4; r++) {
        float v = fmaxf(s[r], 0.f);
        astu(Opub + (size_t)(a0 + quad * 4 + r) * H_ + j0 + col, packf(v));
      }
    }
  }
  rendezvous(cnt, slot++);
  // ---- y = relu(o @ W_o): 32 tiles on blocks 0..1 (full-K) ----
  if (wg < 2) {
    int id = wg * 16 + wv;            // 0..31
    int bt2 = id & 1, jt2 = id >> 1;  // jt2 0..15
    f32x4 acc = {0.f, 0.f, 0.f, 0.f};
    acc = mm_tile_pf(Opub, bt2 * 16, WoT_hi, WoT_lo, jt2 * 16, acc, col, quad);
#pragma unroll
    for (int r = 0; r < 4; r++) {
      float v = fmaxf(acc[r], 0.f);
      size_t idx = (size_t)(bt2 * 16 + quad * 4 + r) * NOUT_ + jt2 * 16 + col;
      if (isf32) ((float*)y_out)[idx] = v;
      else       ((unsigned short*)y_out)[idx] = f2bf(v);
    }
  }
}

extern "C" void kernel_launch(void* const* d_in, const int* in_sizes, int n_in,
                              void* d_out, int out_size, void* d_ws, size_t ws_size,
                              hipStream_t stream) {
  const void* x_in = d_in[0];
  const void* W_i  = d_in[1];
  const void* W_z  = d_in[2];
  const void* W_c  = d_in[3];
  const void* W_h  = d_in[4];
  const void* W_ho = d_in[5];
  const void* W_o  = d_in[6];
  const void* lam  = d_in[7];
  const void* eta  = d_in[8];
  const void* g    = d_in[9];
  const void* bb   = d_in[10];

  char* wsp = (char*)d_ws;
  size_t off = 0;
  auto alloc = [&](size_t bytes) {
    void* p = wsp + off;
    off += (bytes + 255) & ~(size_t)255;
    return p;
  };
  int*            flag    = (int*)alloc(16);
  int*            cnt     = (int*)alloc(NSLOT * 4);
  float*          par     = (float*)alloc((2 + 2 * H_) * 4);
  unsigned int*   X_pk    = (unsigned int*)alloc((size_t)T_ * B_ * NIN_ * 4);
  unsigned short* WiT_hi  = (unsigned short*)alloc((size_t)NIN_ * H_ * 2);
  unsigned short* WiT_lo  = (unsigned short*)alloc((size_t)NIN_ * H_ * 2);
  unsigned short* WzT_hi  = (unsigned short*)alloc((size_t)H_ * H_ * 2);
  unsigned short* WzT_lo  = (unsigned short*)alloc((size_t)H_ * H_ * 2);
  unsigned short* WcT_hi  = (unsigned short*)alloc((size_t)H_ * H_ * 2);
  unsigned short* WcT_lo  = (unsigned short*)alloc((size_t)H_ * H_ * 2);
  unsigned short* WhT_hi  = (unsigned short*)alloc((size_t)H_ * H_ * 2);
  unsigned short* WhT_lo  = (unsigned short*)alloc((size_t)H_ * H_ * 2);
  unsigned short* WhoT_hi = (unsigned short*)alloc((size_t)H_ * H_ * 2);
  unsigned short* WhoT_lo = (unsigned short*)alloc((size_t)H_ * H_ * 2);
  unsigned short* WoT_hi  = (unsigned short*)alloc((size_t)H_ * NOUT_ * 2);
  unsigned short* WoT_lo  = (unsigned short*)alloc((size_t)H_ * NOUT_ * 2);
  unsigned int*   S_pk    = (unsigned int*)alloc((size_t)T_ * B_ * H_ * 4);
  unsigned int*   Z_pk    = (unsigned int*)alloc((size_t)T_ * B_ * H_ * 4);
  float*          ZC      = (float*)alloc((size_t)T_ * B_ * H_ * 4);
  unsigned int*   hq      = (unsigned int*)alloc((size_t)T_ * B_ * H_ * 4);
  unsigned int*   hc      = (unsigned int*)alloc((size_t)(T_ + 1) * B_ * H_ * 4);
  unsigned int*   Opub    = (unsigned int*)alloc((size_t)B_ * H_ * 4);
  float*          histloc = (float*)alloc((size_t)NBLK * T_ * B_ * NCOL * 4);
  float*          dots_g  = (float*)alloc((size_t)T_ * B_ * T_ * 4);
  (void)ws_size; (void)in_sizes; (void)n_in; (void)out_size;

  // 1. detect dtype + zero counters
  init_detect<<<1, 256, 0, stream>>>((const unsigned short*)x_in, flag, cnt);

  // 2. fused prep: pack x | params | all 6 transposes (one launch)
  prep_all<<<PACKB + 4 + 4864, 256, 0, stream>>>(
      x_in, X_pk, lam, eta, g, bb, par,
      W_i, WiT_hi, WiT_lo, W_z, WzT_hi, WzT_lo, W_c, WcT_hi, WcT_lo,
      W_h, WhT_hi, WhT_lo, W_ho, WhoT_hi, WhoT_lo, W_o, WoT_hi, WoT_lo,
      flag);

  // 3. phase A (LDS-tiled 64x64 + reg-prefetch): S, Z, ZC
  gemmT<NIN_, 1><<<256, 1024, 0, stream>>>(X_pk, WiT_hi, WiT_lo, S_pk);
  gemmT<H_,   1><<<256, 1024, 0, stream>>>(S_pk, WzT_hi, WzT_lo, Z_pk);
  gemmT<H_,   0><<<256, 1024, 0, stream>>>(Z_pk, WcT_hi, WcT_lo, ZC);

  // 4. phase B: recurrence + readout, 64-block 16-col K-split GEMMs (r5 verified)
  recurrent<<<NBLK, NTHR, 0, stream>>>(WhT_hi, WhT_lo, WhoT_hi, WhoT_lo, WoT_hi, WoT_lo,
                                       ZC, hq, hc, Opub, histloc, dots_g,
                                       par, d_out, cnt, flag);
}